// Round 3
// baseline (708.159 us; speedup 1.0000x reference)
//
#include <hip/hip_runtime.h>
#include <hip/hip_bf16.h>
#include <stdint.h>

#define DEVI __device__ __forceinline__

using bf16 = __hip_bfloat16;

typedef __bf16 bf16x8 __attribute__((ext_vector_type(8)));
typedef float f32x4 __attribute__((ext_vector_type(4)));

constexpr int BATCH = 4, NH = 16, SEQ = 2048, HD = 128, DMODEL = 2048;
constexpr int MROWS = BATCH * SEQ;  // 8192

DEVI f32x4 mfma16(uint4 a, uint4 b, f32x4 c) {
  return __builtin_amdgcn_mfma_f32_16x16x32_bf16(
      __builtin_bit_cast(bf16x8, a), __builtin_bit_cast(bf16x8, b), c, 0, 0, 0);
}

DEVI unsigned pack2(float a, float b) {
  __hip_bfloat16 ha = __float2bfloat16(a), hb = __float2bfloat16(b);
  unsigned short ua = __builtin_bit_cast(unsigned short, ha);
  unsigned short ub = __builtin_bit_cast(unsigned short, hb);
  return ((unsigned)ub << 16) | (unsigned)ua;
}

DEVI void gload16(const void* g, void* l) {
  auto gp = reinterpret_cast<__attribute__((address_space(1))) unsigned int*>(
      reinterpret_cast<uintptr_t>(g));
  auto lp = reinterpret_cast<__attribute__((address_space(3))) unsigned int*>(
      reinterpret_cast<uintptr_t>(l));
  __builtin_amdgcn_global_load_lds(gp, lp, 16, 0, 0);
}

// ---------------- cast x (fp32 -> bf16), vectorized ----------------
__global__ void cast_x_kernel(const float* __restrict__ in, bf16* __restrict__ out, int n8) {
  for (int i = blockIdx.x * blockDim.x + threadIdx.x; i < n8; i += gridDim.x * blockDim.x) {
    const float4* p = (const float4*)in + (size_t)i * 2;
    float4 a = p[0], b = p[1];
    uint4 u;
    u.x = pack2(a.x, a.y);
    u.y = pack2(a.z, a.w);
    u.z = pack2(b.x, b.y);
    u.w = pack2(b.z, b.w);
    *((uint4*)out + i) = u;
  }
}

// ------------- transpose-cast W [K][N] fp32 -> Wt [N][K] bf16 -------------
__global__ void transpose_w_kernel(const float* __restrict__ W0, const float* __restrict__ W1,
                                   const float* __restrict__ W2, bf16* __restrict__ WtBase) {
  const int z = blockIdx.z;
  const float* W = (z == 0) ? W0 : (z == 1) ? W1 : W2;
  bf16* Wt = WtBase + (size_t)z * DMODEL * DMODEL;
  __shared__ float tile[64][65];
  const int k0 = blockIdx.x * 64, n0 = blockIdx.y * 64;
  const int tid = threadIdx.x;
  for (int i = tid; i < 4096; i += 256) {
    int r = i >> 6, c = i & 63;
    tile[r][c] = W[(size_t)(k0 + r) * DMODEL + n0 + c];
  }
  __syncthreads();
  for (int i = tid; i < 4096; i += 256) {
    int r = i >> 6, c = i & 63;  // r = n index, c = k index
    Wt[(size_t)(n0 + r) * DMODEL + k0 + c] = __float2bfloat16(tile[c][r]);
  }
}

// ---------------- bf16 GEMM, 2-phase double-buffered ----------------
// C[m][n] = sum_k A[m][k] * Bt[n][k] + bias[n]
// transposed==0: Cout[bh][s][d]  (Q, K layout);  ==1: Cout[bh][d][s]  (V^T layout)
__global__ __launch_bounds__(256) void gemm_bf16(
    const bf16* __restrict__ A, const bf16* __restrict__ Bt,
    const float* __restrict__ bias, bf16* __restrict__ Cout, int transposed) {
  __shared__ __align__(16) bf16 As[2][128][32];
  __shared__ __align__(16) bf16 Bs[2][128][32];
  const int tid = threadIdx.x;
  const int lane = tid & 63, wave = tid >> 6;
  const int lr = lane & 15, lg = lane >> 4;
  const int m0 = blockIdx.x * 128, n0 = blockIdx.y * 128;
  const int wr = wave >> 1, wc = wave & 1;

  f32x4 acc[4][4];
#pragma unroll
  for (int i = 0; i < 4; ++i)
#pragma unroll
    for (int j = 0; j < 4; ++j) acc[i][j] = (f32x4){0.f, 0.f, 0.f, 0.f};

  const char* ag = (const char*)(A + (size_t)(m0 + (tid >> 2)) * DMODEL) + (tid & 3) * 16;
  const char* bg = (const char*)(Bt + (size_t)(n0 + (tid >> 2)) * DMODEL) + (tid & 3) * 16;
  char* asw = (char*)As + wave * 1024;
  char* bsw = (char*)Bs + wave * 1024;
  constexpr size_t rowadv = (size_t)64 * DMODEL * 2;

  // prologue: stage k=0 into buf 0
  gload16(ag, asw);
  gload16(ag + rowadv, asw + 4096);
  gload16(bg, bsw);
  gload16(bg + rowadv, bsw + 4096);
  __syncthreads();

  int cur = 0;
  for (int k0 = 0; k0 < DMODEL; k0 += 32) {
    // stage next K-step into the other buffer (in flight across the MFMAs)
    if (k0 + 32 < DMODEL) {
      int nb = (cur ^ 1) * 8192;
      gload16(ag + (k0 + 32) * 2, asw + nb);
      gload16(ag + (k0 + 32) * 2 + rowadv, asw + nb + 4096);
      gload16(bg + (k0 + 32) * 2, bsw + nb);
      gload16(bg + (k0 + 32) * 2 + rowadv, bsw + nb + 4096);
    }
    uint4 af[4], bfr[4];
#pragma unroll
    for (int i = 0; i < 4; ++i) af[i] = *(const uint4*)&As[cur][wr * 64 + i * 16 + lr][lg * 8];
#pragma unroll
    for (int j = 0; j < 4; ++j) bfr[j] = *(const uint4*)&Bs[cur][wc * 64 + j * 16 + lr][lg * 8];
#pragma unroll
    for (int i = 0; i < 4; ++i)
#pragma unroll
      for (int j = 0; j < 4; ++j) acc[i][j] = mfma16(af[i], bfr[j], acc[i][j]);
    __syncthreads();  // drains vmcnt(0)+lgkmcnt(0): next buf staged, cur free
    cur ^= 1;
  }

  float bvals[4];
#pragma unroll
  for (int nf = 0; nf < 4; ++nf) bvals[nf] = bias[n0 + wc * 64 + nf * 16 + lr];

  const int bh = ((m0 >> 11) << 4) | (n0 >> 7);
  const int sbase = (m0 & 2047) + wr * 64;
  if (!transposed) {
    bf16* base = Cout + (size_t)bh * SEQ * HD;
#pragma unroll
    for (int mf = 0; mf < 4; ++mf)
#pragma unroll
      for (int nf = 0; nf < 4; ++nf) {
        int d = wc * 64 + nf * 16 + lr;
#pragma unroll
        for (int jj = 0; jj < 4; ++jj) {
          int s = sbase + mf * 16 + lg * 4 + jj;
          base[(size_t)s * HD + d] = __float2bfloat16(acc[mf][nf][jj] + bvals[nf]);
        }
      }
  } else {
    bf16* base = Cout + (size_t)bh * HD * SEQ;
#pragma unroll
    for (int mf = 0; mf < 4; ++mf)
#pragma unroll
      for (int nf = 0; nf < 4; ++nf) {
        int d = wc * 64 + nf * 16 + lr;
        int s0 = sbase + mf * 16 + lg * 4;
        uint2 u;
        u.x = pack2(acc[mf][nf][0] + bvals[nf], acc[mf][nf][1] + bvals[nf]);
        u.y = pack2(acc[mf][nf][2] + bvals[nf], acc[mf][nf][3] + bvals[nf]);
        *(uint2*)&base[(size_t)d * SEQ + s0] = u;
      }
  }
}

// ---------------- flash attention, causal ----------------
// Q,K: [BH][S][D] bf16;  Vt: [BH][D][S] bf16;  out: [B][S][H*D] fp32
// 8 waves/block (512 thr), 16 q-rows/wave -> block = 128-row q-tile.
// Block processes q-tile pair (pi, 15-pi) sequentially: uniform 36 kv-tile
// iterations/block. K staged in dbuf swizzled LDS (global_load_lds); V^T read
// direct from global (L2-resident). P via per-wave stride-144 LDS buffer.
// Grid 512 = exactly 2 blocks/CU; launch_bounds(512,4) -> 4 waves/SIMD.
__global__ __launch_bounds__(512, 4) void attn_kernel(
    const bf16* __restrict__ Q, const bf16* __restrict__ K,
    const bf16* __restrict__ Vt, float* __restrict__ out) {
  extern __shared__ __align__(16) char smem[];
  char* KsB = smem;            // 2 x 16384  (K tile [64][128] bf16, swizzled)
  char* plB = smem + 32768;    // 8 x 2304   (per-wave P buffer [16 q][stride 144B])

  const int tid = threadIdx.x;
  const int lane = tid & 63;
  const int wave = tid >> 6;
  const int lr = lane & 15, lg = lane >> 4;
  const unsigned swl = ((unsigned)(lr & 7)) << 4;

  const int lid = blockIdx.x;
  const int xcd = lid & 7, slot = lid >> 3;       // slot 0..63
  const int bh = xcd * 8 + (slot >> 3);
  const int pi = slot & 7;                        // pair index 0..7
  const int b = bh >> 4, h = bh & 15;

  const bf16* Qp = Q + (size_t)bh * SEQ * HD;
  const char* Kg0 = (const char*)(K + (size_t)bh * SEQ * HD);
  const bf16* Vp = Vt + (size_t)bh * HD * SEQ;
  char* bp = plB + wave * 2304 + lr * 144;        // this lane's P row (q=lr)

  const float C2 = 0.08838834764831845f * 1.44269504088896f;  // 1/sqrt(128)*log2(e)
  const float THR = 8.0f;                                     // defer-rescale threshold
  int cur = 0;

  for (int sec = 0; sec < 2; ++sec) {
    const int qt = (sec == 0) ? pi : (15 - pi);   // q-tile (128 rows)
    const int q0 = qt * 128 + wave * 16;          // this wave's 16 q-rows
    const int nt = 2 * qt + 2;                    // block kv-tile count
    const int nt_w = (q0 + 79) >> 6;              // this wave's useful tiles
    const int qg = q0 + lr;

    // Q fragment (B-operand): q col = lr, d chunk = dc*32 + lg*8
    uint4 qfrag[4];
    {
      const bf16* qrow = Qp + (size_t)qg * HD + lg * 8;
#pragma unroll
      for (int dc = 0; dc < 4; ++dc) qfrag[dc] = *(const uint4*)(qrow + dc * 32);
    }

    f32x4 acc[8];
#pragma unroll
    for (int df = 0; df < 8; ++df) acc[df] = (f32x4){0.f, 0.f, 0.f, 0.f};
    float m_run = -1e30f, l_run = 0.f;

    // ---- prologue stage: tile 0 -> buf[cur] ----
    {
      char* kl = KsB + cur * 16384 + tid * 16;
#pragma unroll
      for (int r = 0; r < 2; ++r) {
        int o = r * 8192 + tid * 16;
        int krow = o >> 8; unsigned kcb = o & 255;
        gload16(Kg0 + krow * 256 + (kcb ^ (((unsigned)(krow & 7)) << 4)), kl + r * 8192);
      }
    }
    __syncthreads();

    for (int t = 0; t < nt; ++t) {
      // ---- stage next K tile into buf[cur^1] (overlaps compute) ----
      if (t + 1 < nt) {
        const char* Kg = Kg0 + ((size_t)(t + 1) << 14);
        char* kl = KsB + (cur ^ 1) * 16384 + tid * 16;
#pragma unroll
        for (int r = 0; r < 2; ++r) {
          int o = r * 8192 + tid * 16;
          int krow = o >> 8; unsigned kcb = o & 255;
          gload16(Kg + krow * 256 + (kcb ^ (((unsigned)(krow & 7)) << 4)), kl + r * 8192);
        }
      }

      if (t < nt_w) {  // wave-level skip of fully-masked tiles (still hits barriers)
        const int kv0 = t << 6;
        const char* kb = KsB + cur * 16384;

        // ---- S^T = K * Q^T ----
        f32x4 sfr[4];
#pragma unroll
        for (int kvf = 0; kvf < 4; ++kvf) {
          sfr[kvf] = (f32x4){0.f, 0.f, 0.f, 0.f};
          const char* krow = kb + (kvf * 16 + lr) * 256;
#pragma unroll
          for (int dc = 0; dc < 4; ++dc) {
            uint4 ka = *(const uint4*)(krow + (((unsigned)(dc * 64 + lg * 16)) ^ swl));
            sfr[kvf] = mfma16(ka, qfrag[dc], sfr[kvf]);
          }
        }

        // ---- online softmax (base-2), defer-rescale ----
        const bool need_mask = (kv0 + 63) > q0;
        float mx = -1e30f;
#pragma unroll
        for (int kvf = 0; kvf < 4; ++kvf)
#pragma unroll
          for (int j = 0; j < 4; ++j) {
            float v = sfr[kvf][j] * C2;
            if (need_mask) {
              int kvgl = kv0 + kvf * 16 + lg * 4 + j;
              v = (kvgl <= qg) ? v : -1e30f;
            }
            sfr[kvf][j] = v;
            mx = fmaxf(mx, v);
          }
        mx = fmaxf(mx, __shfl_xor(mx, 16));
        mx = fmaxf(mx, __shfl_xor(mx, 32));
        if (!__all(mx <= m_run + THR)) {  // wave-uniform rescale (rare once warm)
          float mnew = fmaxf(m_run, mx);
          float corr = exp2f(m_run - mnew);
          l_run *= corr;
#pragma unroll
          for (int df = 0; df < 8; ++df) acc[df] *= corr;
          m_run = mnew;
        }
        float ps = 0.f;
#pragma unroll
        for (int kvf = 0; kvf < 4; ++kvf) {
          float p0 = exp2f(sfr[kvf][0] - m_run);
          float p1 = exp2f(sfr[kvf][1] - m_run);
          float p2 = exp2f(sfr[kvf][2] - m_run);
          float p3 = exp2f(sfr[kvf][3] - m_run);
          ps += p0 + p1 + p2 + p3;
          unsigned off = (unsigned)(kvf * 32 + lg * 8);
          *(unsigned*)(bp + off) = pack2(p0, p1);
          *(unsigned*)(bp + off + 4) = pack2(p2, p3);
        }
        ps += __shfl_xor(ps, 16);
        ps += __shfl_xor(ps, 32);
        l_run += ps;

        // cross-lane P RAW within wave: drain DS queue, fence reordering
        asm volatile("s_waitcnt lgkmcnt(0)" ::: "memory");

        // ---- read P^T B-fragments (stride-144 rows: conflict-free) ----
        uint4 pb0 = *(uint4*)(bp + lg * 16);
        uint4 pb1 = *(uint4*)(bp + 64 + lg * 16);

        // ---- O^T += V^T * P^T  (V^T from global, L2-resident) ----
#pragma unroll
        for (int df = 0; df < 8; ++df) {
          const bf16* vrow = Vp + (size_t)(df * 16 + lr) * SEQ + kv0 + lg * 8;
          uint4 va0 = *(const uint4*)(vrow);
          uint4 va1 = *(const uint4*)(vrow + 32);
          acc[df] = mfma16(va0, pb0, acc[df]);
          acc[df] = mfma16(va1, pb1, acc[df]);
        }
      }

      __syncthreads();  // next buffer staged (vmcnt drained); cur free to overwrite
      cur ^= 1;
    }

    // ---- epilogue: normalize, write fp32 out[b][s][h*D + d] ----
    {
      float inv = 1.f / l_run;
      size_t rowoff = ((size_t)b * SEQ + (size_t)qg) * DMODEL + h * HD;
#pragma unroll
      for (int df = 0; df < 8; ++df) {
        float4 o;
        o.x = acc[df][0] * inv;
        o.y = acc[df][1] * inv;
        o.z = acc[df][2] * inv;
        o.w = acc[df][3] * inv;
        *(float4*)(out + rowoff + df * 16 + lg * 4) = o;
      }
    }
  }
}

extern "C" void kernel_launch(void* const* d_in, const int* in_sizes, int n_in,
                              void* d_out, int out_size, void* d_ws, size_t ws_size,
                              hipStream_t stream) {
  const float* x = (const float*)d_in[0];
  const float* Wq = (const float*)d_in[1];
  const float* bq = (const float*)d_in[2];
  const float* Wk = (const float*)d_in[3];
  const float* bk = (const float*)d_in[4];
  const float* Wv = (const float*)d_in[5];
  const float* bv = (const float*)d_in[6];
  float* out = (float*)d_out;

  const size_t sz_x = (size_t)MROWS * DMODEL * 2;
  const size_t sz_w = (size_t)DMODEL * DMODEL * 2;
  const size_t sz_qkv = (size_t)MROWS * DMODEL * 2;
  if (ws_size < sz_x + 3 * sz_w + 3 * sz_qkv) return;

  char* w = (char*)d_ws;
  bf16* xb = (bf16*)w;  w += sz_x;
  bf16* WtQ = (bf16*)w; w += sz_w;
  bf16* WtK = (bf16*)w; w += sz_w;
  bf16* WtV = (bf16*)w; w += sz_w;
  bf16* Qb = (bf16*)w;  w += sz_qkv;
  bf16* Kb = (bf16*)w;  w += sz_qkv;
  bf16* Vtb = (bf16*)w; w += sz_qkv;

  cast_x_kernel<<<2048, 256, 0, stream>>>(x, xb, MROWS * DMODEL / 8);
  transpose_w_kernel<<<dim3(32, 32, 3), 256, 0, stream>>>(Wq, Wk, Wv, WtQ);
  gemm_bf16<<<dim3(64, 16), 256, 0, stream>>>(xb, WtQ, bq, Qb, 0);
  gemm_bf16<<<dim3(64, 16), 256, 0, stream>>>(xb, WtK, bk, Kb, 0);
  gemm_bf16<<<dim3(64, 16), 256, 0, stream>>>(xb, WtV, bv, Vtb, 1);
  attn_kernel<<<dim3(512), 512, 51200, stream>>>(Qb, Kb, Vtb, out);
}

// Round 4
// 586.784 us; speedup vs baseline: 1.2068x; 1.2068x over previous
//
#include <hip/hip_runtime.h>
#include <hip/hip_bf16.h>
#include <stdint.h>

#define DEVI __device__ __forceinline__

using bf16 = __hip_bfloat16;

typedef __bf16 bf16x8 __attribute__((ext_vector_type(8)));
typedef short s16x4 __attribute__((ext_vector_type(4)));
typedef float f32x4 __attribute__((ext_vector_type(4)));

constexpr int BATCH = 4, NH = 16, SEQ = 2048, HD = 128, DMODEL = 2048;
constexpr int MROWS = BATCH * SEQ;  // 8192

DEVI f32x4 mfma32(uint4 a, uint4 b, f32x4 c) {
  return __builtin_amdgcn_mfma_f32_16x16x32_bf16(
      __builtin_bit_cast(bf16x8, a), __builtin_bit_cast(bf16x8, b), c, 0, 0, 0);
}

// K=16 bf16 MFMA: B-operand layout (col=lr, k=lg*4+{0..3}) matches the
// 16x16 C/D layout of QK^T exactly -> P feeds PV with no cross-lane exchange.
DEVI f32x4 mfma16k(uint2 a, uint2 b, f32x4 c) {
#if __has_builtin(__builtin_amdgcn_mfma_f32_16x16x16bf16_1k)
  return __builtin_amdgcn_mfma_f32_16x16x16bf16_1k(
      __builtin_bit_cast(s16x4, a), __builtin_bit_cast(s16x4, b), c, 0, 0, 0);
#else
  f32x4 d;
  asm("v_mfma_f32_16x16x16_bf16 %0, %1, %2, %3"
      : "=v"(d) : "v"(a), "v"(b), "v"(c));
  return d;
#endif
}

DEVI unsigned pack2(float a, float b) {
  __hip_bfloat16 ha = __float2bfloat16(a), hb = __float2bfloat16(b);
  unsigned short ua = __builtin_bit_cast(unsigned short, ha);
  unsigned short ub = __builtin_bit_cast(unsigned short, hb);
  return ((unsigned)ub << 16) | (unsigned)ua;
}

DEVI void gload16(const void* g, void* l) {
  auto gp = reinterpret_cast<__attribute__((address_space(1))) unsigned int*>(
      reinterpret_cast<uintptr_t>(g));
  auto lp = reinterpret_cast<__attribute__((address_space(3))) unsigned int*>(
      reinterpret_cast<uintptr_t>(l));
  __builtin_amdgcn_global_load_lds(gp, lp, 16, 0, 0);
}

// ---------------- cast x (fp32 -> bf16), vectorized ----------------
__global__ void cast_x_kernel(const float* __restrict__ in, bf16* __restrict__ out, int n8) {
  for (int i = blockIdx.x * blockDim.x + threadIdx.x; i < n8; i += gridDim.x * blockDim.x) {
    const float4* p = (const float4*)in + (size_t)i * 2;
    float4 a = p[0], b = p[1];
    uint4 u;
    u.x = pack2(a.x, a.y);
    u.y = pack2(a.z, a.w);
    u.z = pack2(b.x, b.y);
    u.w = pack2(b.z, b.w);
    *((uint4*)out + i) = u;
  }
}

// ------------- transpose-cast W [K][N] fp32 -> Wt [N][K] bf16 -------------
__global__ void transpose_w_kernel(const float* __restrict__ W0, const float* __restrict__ W1,
                                   const float* __restrict__ W2, bf16* __restrict__ WtBase) {
  const int z = blockIdx.z;
  const float* W = (z == 0) ? W0 : (z == 1) ? W1 : W2;
  bf16* Wt = WtBase + (size_t)z * DMODEL * DMODEL;
  __shared__ float tile[64][65];
  const int k0 = blockIdx.x * 64, n0 = blockIdx.y * 64;
  const int tid = threadIdx.x;
  for (int i = tid; i < 4096; i += 256) {
    int r = i >> 6, c = i & 63;
    tile[r][c] = W[(size_t)(k0 + r) * DMODEL + n0 + c];
  }
  __syncthreads();
  for (int i = tid; i < 4096; i += 256) {
    int r = i >> 6, c = i & 63;  // r = n index, c = k index
    Wt[(size_t)(n0 + r) * DMODEL + k0 + c] = __float2bfloat16(tile[c][r]);
  }
}

// ---------------- bf16 GEMM, 2-phase double-buffered ----------------
// C[m][n] = sum_k A[m][k] * Bt[n][k] + bias[n]
// TR==0: Cout[bh][s][d] (Q,K) with operand-swapped mfma -> d-packed 8B stores.
// TR==1: Cout[bh][d][s] (V^T) -> s-packed 8B stores.
template <int TR>
__global__ __launch_bounds__(256) void gemm_bf16(
    const bf16* __restrict__ A, const bf16* __restrict__ Bt,
    const float* __restrict__ bias, bf16* __restrict__ Cout) {
  __shared__ __align__(16) bf16 As[2][128][32];
  __shared__ __align__(16) bf16 Bs[2][128][32];
  const int tid = threadIdx.x;
  const int lane = tid & 63, wave = tid >> 6;
  const int lr = lane & 15, lg = lane >> 4;
  // XCD swizzle: XCD g owns n-tiles {2g,2g+1} (B-panels L2-hot), sweeps m.
  const int lid = blockIdx.y * gridDim.x + blockIdx.x;   // 0..1023, x fastest
  const int g = lid & 7, kk = lid >> 3;                  // kk 0..127
  const int m0 = (kk & 63) * 128;
  const int n0 = ((g << 1) | (kk >> 6)) * 128;
  const int wr = wave >> 1, wc = wave & 1;

  f32x4 acc[4][4];
#pragma unroll
  for (int i = 0; i < 4; ++i)
#pragma unroll
    for (int j = 0; j < 4; ++j) acc[i][j] = (f32x4){0.f, 0.f, 0.f, 0.f};

  const char* ag = (const char*)(A + (size_t)(m0 + (tid >> 2)) * DMODEL) + (tid & 3) * 16;
  const char* bg = (const char*)(Bt + (size_t)(n0 + (tid >> 2)) * DMODEL) + (tid & 3) * 16;
  char* asw = (char*)As + wave * 1024;
  char* bsw = (char*)Bs + wave * 1024;
  constexpr size_t rowadv = (size_t)64 * DMODEL * 2;

  // prologue: stage k=0 into buf 0
  gload16(ag, asw);
  gload16(ag + rowadv, asw + 4096);
  gload16(bg, bsw);
  gload16(bg + rowadv, bsw + 4096);
  __syncthreads();

  int cur = 0;
  for (int k0 = 0; k0 < DMODEL; k0 += 32) {
    if (k0 + 32 < DMODEL) {
      int nb = (cur ^ 1) * 8192;
      gload16(ag + (k0 + 32) * 2, asw + nb);
      gload16(ag + (k0 + 32) * 2 + rowadv, asw + nb + 4096);
      gload16(bg + (k0 + 32) * 2, bsw + nb);
      gload16(bg + (k0 + 32) * 2 + rowadv, bsw + nb + 4096);
    }
    uint4 af[4], bfr[4];
#pragma unroll
    for (int i = 0; i < 4; ++i) af[i] = *(const uint4*)&As[cur][wr * 64 + i * 16 + lr][lg * 8];
#pragma unroll
    for (int j = 0; j < 4; ++j) bfr[j] = *(const uint4*)&Bs[cur][wc * 64 + j * 16 + lr][lg * 8];
#pragma unroll
    for (int i = 0; i < 4; ++i)
#pragma unroll
      for (int j = 0; j < 4; ++j) {
        if (TR == 0)
          acc[i][j] = mfma32(bfr[j], af[i], acc[i][j]);  // D[n][m]: col=m, row=n
        else
          acc[i][j] = mfma32(af[i], bfr[j], acc[i][j]);  // D[m][n]: col=n, row=m
      }
    __syncthreads();
    cur ^= 1;
  }

  const int bh = ((m0 >> 11) << 4) | (n0 >> 7);
  const int sbase = (m0 & 2047) + wr * 64;
  if (TR == 0) {
    bf16* base = Cout + (size_t)bh * SEQ * HD;
#pragma unroll
    for (int j = 0; j < 4; ++j) {
      const int d0 = wc * 64 + j * 16 + lg * 4;
      float4 bb = *(const float4*)&bias[n0 + d0];
#pragma unroll
      for (int i = 0; i < 4; ++i) {
        int s = sbase + i * 16 + lr;
        uint2 u;
        u.x = pack2(acc[i][j][0] + bb.x, acc[i][j][1] + bb.y);
        u.y = pack2(acc[i][j][2] + bb.z, acc[i][j][3] + bb.w);
        *(uint2*)&base[(size_t)s * HD + d0] = u;
      }
    }
  } else {
    float bvals[4];
#pragma unroll
    for (int nf = 0; nf < 4; ++nf) bvals[nf] = bias[n0 + wc * 64 + nf * 16 + lr];
    bf16* base = Cout + (size_t)bh * HD * SEQ;
#pragma unroll
    for (int mf = 0; mf < 4; ++mf)
#pragma unroll
      for (int nf = 0; nf < 4; ++nf) {
        int d = wc * 64 + nf * 16 + lr;
        int s0 = sbase + mf * 16 + lg * 4;
        uint2 u;
        u.x = pack2(acc[mf][nf][0] + bvals[nf], acc[mf][nf][1] + bvals[nf]);
        u.y = pack2(acc[mf][nf][2] + bvals[nf], acc[mf][nf][3] + bvals[nf]);
        *(uint2*)&base[(size_t)d * SEQ + s0] = u;
      }
  }
}

// ---------------- flash attention, causal ----------------
// Q,K: [BH][S][D] bf16;  Vt: [BH][D][S] bf16;  out: [B][S][H*D] fp32
// 4 waves/block (256 thr), 32 q-rows/wave; block = 128-row q-tile, does pair
// (pi, 15-pi) sequentially (uniform 36 kv-tiles). K and V^T double-buffered in
// XOR-swizzled LDS (64 KB -> 2 blocks/CU). PV uses 16x16x16 MFMA so the QK^T
// output layout feeds P directly as B-operand: no P LDS buffer, no fence.
__global__ __launch_bounds__(256, 2) void attn_kernel(
    const bf16* __restrict__ Q, const bf16* __restrict__ K,
    const bf16* __restrict__ Vt, float* __restrict__ out) {
  extern __shared__ __align__(16) char smem[];
  char* KsB = smem;           // 2 x 16384 : K tile [64 kv][128 d], row-swizzled
  char* VsB = smem + 32768;   // 2 x 16384 : V^T tile [128 d][64 kv], row-swizzled

  const int tid = threadIdx.x;
  const int lane = tid & 63;
  const int wave = tid >> 6;  // 0..3
  const int lr = lane & 15, lg = lane >> 4;
  const unsigned swl = ((unsigned)(lr & 7)) << 4;

  const int lid = blockIdx.x;                     // 512 blocks = 2/CU
  const int xcd = lid & 7, slot = lid >> 3;       // all 8 pairs of a bh on one XCD
  const int bh = xcd * 8 + (slot >> 3);
  const int pi = slot & 7;
  const int b = bh >> 4, h = bh & 15;

  const bf16* Qp = Q + (size_t)bh * SEQ * HD;
  const char* Kg0 = (const char*)(K + (size_t)bh * SEQ * HD);
  const char* Vg0 = (const char*)(Vt + (size_t)bh * HD * SEQ);

  const float C2 = 0.08838834764831845f * 1.44269504088896f;  // 1/sqrt(128)*log2(e)
  const float THR = 8.0f;  // defer-rescale threshold (log2 units)
  int cur = 0;

  for (int sec = 0; sec < 2; ++sec) {
    const int qt = (sec == 0) ? pi : (15 - pi);
    const int q0 = qt * 128 + wave * 32;
    const int nt = 2 * qt + 2;
    const int nt_w = (q0 + 95) >> 6;
    const int qg[2] = {q0 + lr, q0 + 16 + lr};

    // Q fragments (B-operand of x32): q col = lr, d chunk = dc*32 + lg*8
    uint4 qfrag[2][4];
#pragma unroll
    for (int qf = 0; qf < 2; ++qf) {
      const bf16* qrow = Qp + (size_t)(q0 + qf * 16 + lr) * HD + lg * 8;
#pragma unroll
      for (int dc = 0; dc < 4; ++dc) qfrag[qf][dc] = *(const uint4*)(qrow + dc * 32);
    }

    f32x4 acc[8][2];
#pragma unroll
    for (int df = 0; df < 8; ++df) {
      acc[df][0] = (f32x4){0.f, 0.f, 0.f, 0.f};
      acc[df][1] = (f32x4){0.f, 0.f, 0.f, 0.f};
    }
    float m_run[2] = {-1e30f, -1e30f};
    float l_run[2] = {0.f, 0.f};

    // ---- prologue stage: tile 0 -> buf[cur] ----
    {
      char* kl = KsB + cur * 16384 + tid * 16;
      char* vl = VsB + cur * 16384 + tid * 16;
#pragma unroll
      for (int r = 0; r < 4; ++r) {
        int o = r * 4096 + tid * 16;
        int krow = o >> 8; unsigned kcb = o & 255;
        gload16(Kg0 + krow * 256 + (kcb ^ (((unsigned)(krow & 7)) << 4)), kl + r * 4096);
        int vrow = o >> 7; unsigned vcb = o & 127;
        gload16(Vg0 + (size_t)vrow * 4096 + (vcb ^ (((unsigned)(vrow & 7)) << 4)), vl + r * 4096);
      }
    }
    __syncthreads();

    for (int t = 0; t < nt; ++t) {
      // ---- stage next tile into buf[cur^1] (in flight across the compute) ----
      if (t + 1 < nt) {
        const char* Kg = Kg0 + ((size_t)(t + 1) << 14);   // +64 K-rows * 256 B
        const char* Vg = Vg0 + ((size_t)(t + 1) << 7);    // +64 kv * 2 B
        char* kl = KsB + (cur ^ 1) * 16384 + tid * 16;
        char* vl = VsB + (cur ^ 1) * 16384 + tid * 16;
#pragma unroll
        for (int r = 0; r < 4; ++r) {
          int o = r * 4096 + tid * 16;
          int krow = o >> 8; unsigned kcb = o & 255;
          gload16(Kg + krow * 256 + (kcb ^ (((unsigned)(krow & 7)) << 4)), kl + r * 4096);
          int vrow = o >> 7; unsigned vcb = o & 127;
          gload16(Vg + (size_t)vrow * 4096 + (vcb ^ (((unsigned)(vrow & 7)) << 4)), vl + r * 4096);
        }
      }

      if (t < nt_w) {  // wave-uniform skip of dead tiles (still hits barrier)
        const int kv0 = t << 6;
        const char* kb = KsB + cur * 16384;
        const char* vb = VsB + cur * 16384;

        // ---- S^T = K * Q^T  (x32 MFMA) ----
        f32x4 sfr[4][2];
#pragma unroll
        for (int kvf = 0; kvf < 4; ++kvf) {
          sfr[kvf][0] = (f32x4){0.f, 0.f, 0.f, 0.f};
          sfr[kvf][1] = (f32x4){0.f, 0.f, 0.f, 0.f};
          const char* krow = kb + (kvf * 16 + lr) * 256;
#pragma unroll
          for (int dc = 0; dc < 4; ++dc) {
            uint4 ka = *(const uint4*)(krow + (((unsigned)(dc * 64 + lg * 16)) ^ swl));
            sfr[kvf][0] = mfma32(ka, qfrag[0][dc], sfr[kvf][0]);
            sfr[kvf][1] = mfma32(ka, qfrag[1][dc], sfr[kvf][1]);
          }
        }

        // ---- online softmax (base-2), defer-rescale; pack P in-register ----
        uint2 pfrag[4][2];  // [kvf][qf]: B-operand of x16, k=lg*4+{0..3}
        const bool need_mask = (kv0 + 63) > q0;
#pragma unroll
        for (int qf = 0; qf < 2; ++qf) {
          float mx = -1e30f;
#pragma unroll
          for (int kvf = 0; kvf < 4; ++kvf)
#pragma unroll
            for (int j = 0; j < 4; ++j) {
              float v = sfr[kvf][qf][j] * C2;
              if (need_mask) {
                int kvgl = kv0 + kvf * 16 + lg * 4 + j;
                v = (kvgl <= qg[qf]) ? v : -1e30f;
              }
              sfr[kvf][qf][j] = v;
              mx = fmaxf(mx, v);
            }
          mx = fmaxf(mx, __shfl_xor(mx, 16));
          mx = fmaxf(mx, __shfl_xor(mx, 32));
          if (!__all(mx <= m_run[qf] + THR)) {
            float mnew = fmaxf(m_run[qf], mx);
            float corr = exp2f(m_run[qf] - mnew);
            l_run[qf] *= corr;
#pragma unroll
            for (int df = 0; df < 8; ++df) acc[df][qf] *= corr;
            m_run[qf] = mnew;
          }
          float ps = 0.f;
#pragma unroll
          for (int kvf = 0; kvf < 4; ++kvf) {
            float p0 = exp2f(sfr[kvf][qf][0] - m_run[qf]);
            float p1 = exp2f(sfr[kvf][qf][1] - m_run[qf]);
            float p2 = exp2f(sfr[kvf][qf][2] - m_run[qf]);
            float p3 = exp2f(sfr[kvf][qf][3] - m_run[qf]);
            ps += p0 + p1 + p2 + p3;
            pfrag[kvf][qf].x = pack2(p0, p1);
            pfrag[kvf][qf].y = pack2(p2, p3);
          }
          ps += __shfl_xor(ps, 16);
          ps += __shfl_xor(ps, 32);
          l_run[qf] += ps;
        }

        // ---- O^T += V^T * P^T  (x16 MFMA, V^T A-frag from swizzled LDS) ----
#pragma unroll
        for (int df = 0; df < 8; ++df) {
          const char* vrow = vb + (df * 16 + lr) * 128;
#pragma unroll
          for (int kvf = 0; kvf < 4; ++kvf) {
            uint2 va = *(const uint2*)(vrow + (((unsigned)(kvf * 32 + lg * 8)) ^ swl));
            acc[df][0] = mfma16k(va, pfrag[kvf][0], acc[df][0]);
            acc[df][1] = mfma16k(va, pfrag[kvf][1], acc[df][1]);
          }
        }
      }

      __syncthreads();  // next buffer staged (vmcnt drained); cur free
      cur ^= 1;
    }

    // ---- epilogue: normalize, write fp32 out[b][s][h*D + d] ----
#pragma unroll
    for (int qf = 0; qf < 2; ++qf) {
      float inv = 1.f / l_run[qf];
      size_t rowoff = ((size_t)b * SEQ + (size_t)qg[qf]) * DMODEL + h * HD;
#pragma unroll
      for (int df = 0; df < 8; ++df) {
        float4 o;
        o.x = acc[df][qf][0] * inv;
        o.y = acc[df][qf][1] * inv;
        o.z = acc[df][qf][2] * inv;
        o.w = acc[df][qf][3] * inv;
        *(float4*)(out + rowoff + df * 16 + lg * 4) = o;
      }
    }
  }
}

extern "C" void kernel_launch(void* const* d_in, const int* in_sizes, int n_in,
                              void* d_out, int out_size, void* d_ws, size_t ws_size,
                              hipStream_t stream) {
  const float* x = (const float*)d_in[0];
  const float* Wq = (const float*)d_in[1];
  const float* bq = (const float*)d_in[2];
  const float* Wk = (const float*)d_in[3];
  const float* bk = (const float*)d_in[4];
  const float* Wv = (const float*)d_in[5];
  const float* bv = (const float*)d_in[6];
  float* out = (float*)d_out;

  const size_t sz_x = (size_t)MROWS * DMODEL * 2;
  const size_t sz_w = (size_t)DMODEL * DMODEL * 2;
  const size_t sz_qkv = (size_t)MROWS * DMODEL * 2;
  if (ws_size < sz_x + 3 * sz_w + 3 * sz_qkv) return;

  char* w = (char*)d_ws;
  bf16* xb = (bf16*)w;  w += sz_x;
  bf16* WtQ = (bf16*)w; w += sz_w;
  bf16* WtK = (bf16*)w; w += sz_w;
  bf16* WtV = (bf16*)w; w += sz_w;
  bf16* Qb = (bf16*)w;  w += sz_qkv;
  bf16* Kb = (bf16*)w;  w += sz_qkv;
  bf16* Vtb = (bf16*)w; w += sz_qkv;

  cast_x_kernel<<<2048, 256, 0, stream>>>(x, xb, MROWS * DMODEL / 8);
  transpose_w_kernel<<<dim3(32, 32, 3), 256, 0, stream>>>(Wq, Wk, Wv, WtQ);
  gemm_bf16<0><<<dim3(64, 16), 256, 0, stream>>>(xb, WtQ, bq, Qb);
  gemm_bf16<0><<<dim3(64, 16), 256, 0, stream>>>(xb, WtK, bk, Kb);
  gemm_bf16<1><<<dim3(64, 16), 256, 0, stream>>>(xb, WtV, bv, Vtb);
  attn_kernel<<<dim3(512), 256, 65536, stream>>>(Qb, Kb, Vtb, out);
}